// Round 2
// 337.147 us; speedup vs baseline: 1.0698x; 1.0698x over previous
//
#include <hip/hip_runtime.h>

// db4 filters as compile-time constants (immediates / s_mov, no K$ loads)
__device__ constexpr float DEC_LO[8] = {
    -0.010597401784997278f, 0.032883011666982945f, 0.030841381835986965f,
    -0.18703481171888114f, -0.02798376941698385f, 0.6308807679295904f,
    0.7148465705525415f, 0.23037781330885523f};
__device__ constexpr float DEC_HI[8] = {
    -0.23037781330885523f, 0.7148465705525415f, -0.6308807679295904f,
    -0.02798376941698385f, 0.18703481171888114f, 0.030841381835986965f,
    -0.032883011666982945f, -0.010597401784997278f};
__device__ constexpr float REC_LO[8] = {
    0.23037781330885523f, 0.7148465705525415f, 0.6308807679295904f,
    -0.02798376941698385f, -0.18703481171888114f, 0.030841381835986965f,
    0.032883011666982945f, -0.010597401784997278f};
__device__ constexpr float REC_HI[8] = {
    -0.010597401784997278f, -0.032883011666982945f, 0.030841381835986965f,
    0.18703481171888114f, -0.02798376941698385f, -0.6308807679295904f,
    0.7148465705525415f, -0.23037781330885523f};

__device__ __forceinline__ float soft_enh(float v, float th) {
    float e = 1.5f * v;
    float a = fabsf(e) - th;
    return a > 0.0f ? copysignf(a, e) : 0.0f;
}

#define TB 32
#define TO 64

// Fused 2D DWT. Row-DWT: 560 row-tasks per block, 2-3 per thread.
// ALL global loads for a thread's tasks are issued before any compute
// (launch_bounds relaxed to (256,4) = 128-VGPR budget so the scheduler
// keeps them in flight -> one vmcnt latency round per block, not ~8-24).
__global__ __launch_bounds__(256, 4) void fused_dwt2_k(
    const float* __restrict__ x, int S, int Nc, int tiles,
    float* __restrict__ aa, float* __restrict__ da,
    float* __restrict__ ad, float* __restrict__ dd,
    unsigned* __restrict__ mx_da, unsigned* __restrict__ mx_ad,
    unsigned* __restrict__ mx_dd)
{
    int b = blockIdx.x;
    int tx = b % tiles, ty = (b / tiles) % tiles, m = b / (tiles * tiles);
    int jh0 = ty * TB, jw0 = tx * TB;
    int r0 = 2 * jh0 - 6, c0 = 2 * jw0 - 6;
    const float* xm = x + (size_t)m * S * S;

    __shared__ float RB[70][68];   // 19,040 B

    int tid = threadIdx.x;
    bool colv = (c0 >= 0) && (c0 + 71 < S);   // vector path: cols in-bounds

    // task slots: e0, e1 always valid (255+256=511 < 560), e2 for tid<48
    int e0 = tid, e1 = tid + 256, e2 = tid + 512;
    bool has2 = (e2 < 560);

    auto prow = [&](int e) -> const float* {
        int pr = r0 + (e >> 3);
        pr = pr < 0 ? -1 - pr : pr;
        pr = pr >= S ? 2 * S - 1 - pr : pr;
        return xm + (size_t)pr * S;
    };

    float f0[16], f1[16], f2[16];
    if (colv) {
        const float* s0 = prow(e0) + (c0 + 8 * (e0 & 7));
        const float* s1 = prow(e1) + (c0 + 8 * (e1 & 7));
#pragma unroll
        for (int i = 0; i < 8; ++i) {
            float2 v = *reinterpret_cast<const float2*>(s0 + 2 * i);
            f0[2 * i] = v.x; f0[2 * i + 1] = v.y;
        }
#pragma unroll
        for (int i = 0; i < 8; ++i) {
            float2 v = *reinterpret_cast<const float2*>(s1 + 2 * i);
            f1[2 * i] = v.x; f1[2 * i + 1] = v.y;
        }
        if (has2) {
            const float* s2 = prow(e2) + (c0 + 8 * (e2 & 7));
#pragma unroll
            for (int i = 0; i < 8; ++i) {
                float2 v = *reinterpret_cast<const float2*>(s2 + 2 * i);
                f2[2 * i] = v.x; f2[2 * i + 1] = v.y;
            }
        }
    } else {
        auto gath = [&](int e, float* f) {
            const float* row = prow(e);
            int base = c0 + 8 * (e & 7);
#pragma unroll
            for (int i = 0; i < 16; ++i) {
                int p = base + i;
                p = p < 0 ? -1 - p : p;
                p = p >= S ? 2 * S - 1 - p : p;
                f[i] = row[p];
            }
        };
        gath(e0, f0);
        gath(e1, f1);
        if (has2) gath(e2, f2);
    }

    auto rdwt = [&](int e, const float* f) {
        float lo[4], hi[4];
#pragma unroll
        for (int i = 0; i < 4; ++i) {
            float alo = 0.f, ahi = 0.f;
#pragma unroll
            for (int t = 0; t < 8; ++t) {
                float v = f[2 * i + 7 - t];
                alo = fmaf(DEC_LO[t], v, alo);
                ahi = fmaf(DEC_HI[t], v, ahi);
            }
            lo[i] = alo; hi[i] = ahi;
        }
        int r = e >> 3, c4 = 4 * (e & 7);
        *reinterpret_cast<float4*>(&RB[r][c4]) = make_float4(lo[0], lo[1], lo[2], lo[3]);
        *reinterpret_cast<float4*>(&RB[r][32 + c4]) = make_float4(hi[0], hi[1], hi[2], hi[3]);
    };
    rdwt(e0, f0);
    rdwt(e1, f1);
    if (has2) rdwt(e2, f2);
    __syncthreads();

    // col dwt: thread owns (jj, 4 consecutive ii), two register-light passes
    int jj = tid & 31, g = tid >> 5;
    int jw = jw0 + jj;
    float mh = 0.f, mv = 0.f, md = 0.f;
#pragma unroll
    for (int pass = 0; pass < 2; ++pass) {
        int rbase = 8 * g + 4 * pass;
        float L[10], H[10];
#pragma unroll
        for (int rr = 0; rr < 10; ++rr) {
            L[rr] = RB[rbase + rr][jj];
            H[rr] = RB[rbase + rr][32 + jj];
        }
#pragma unroll
        for (int k = 0; k < 2; ++k) {
            float vaa = 0.f, vda = 0.f, vad = 0.f, vdd = 0.f;
#pragma unroll
            for (int t = 0; t < 8; ++t) {
                float l = L[2 * k + 7 - t];
                float h = H[2 * k + 7 - t];
                vaa = fmaf(DEC_LO[t], l, vaa);
                vda = fmaf(DEC_HI[t], l, vda);
                vad = fmaf(DEC_LO[t], h, vad);
                vdd = fmaf(DEC_HI[t], h, vdd);
            }
            int jh = jh0 + 4 * g + 2 * pass + k;
            if (jh < Nc && jw < Nc) {
                size_t o = ((size_t)m * Nc + jh) * Nc + jw;
                aa[o] = vaa; da[o] = vda; ad[o] = vad; dd[o] = vdd;
                mh = fmaxf(mh, fabsf(vda));
                mv = fmaxf(mv, fabsf(vad));
                md = fmaxf(md, fabsf(vdd));
            }
        }
    }
#pragma unroll
    for (int off = 32; off; off >>= 1) {
        mh = fmaxf(mh, __shfl_down(mh, off));
        mv = fmaxf(mv, __shfl_down(mv, off));
        md = fmaxf(md, __shfl_down(md, off));
    }
    __shared__ float sm[3][4];
    int wv = tid >> 6, ln = tid & 63;
    if (ln == 0) { sm[0][wv] = mh; sm[1][wv] = mv; sm[2][wv] = md; }
    __syncthreads();
    if (tid == 0) {
        float A = fmaxf(fmaxf(sm[0][0], sm[0][1]), fmaxf(sm[0][2], sm[0][3]));
        float B = fmaxf(fmaxf(sm[1][0], sm[1][1]), fmaxf(sm[1][2], sm[1][3]));
        float C = fmaxf(fmaxf(sm[2][0], sm[2][1]), fmaxf(sm[2][2], sm[2][3]));
        atomicMax(mx_da + m, __float_as_uint(A));
        atomicMax(mx_ad + m, __float_as_uint(B));
        atomicMax(mx_dd + m, __float_as_uint(C));
    }
}

// Fused 2D IDWT. Column-IDWT: per task, preload the 7 needed band rows
// (7 rows x 4 bands = 28 floats) in one batched burst, soft-threshold in
// registers, then run both 4-output passes from registers. One vmcnt
// round per task instead of 40 interleaved dependent scalar loads.
__global__ __launch_bounds__(256, 4) void fused_idwt2_k(
    const float* __restrict__ a, const float* __restrict__ h,
    const float* __restrict__ v, const float* __restrict__ d,
    const unsigned* __restrict__ mxh, const unsigned* __restrict__ mxv,
    const unsigned* __restrict__ mxd,
    int n, int Ho, int tiles, float* __restrict__ out)
{
    int b = blockIdx.x;
    int tx = b % tiles, ty = (b / tiles) % tiles, m = b / (tiles * tiles);
    int i0 = ty * TO, u0 = tx * TO;
    int jr0 = i0 >> 1, jc0 = u0 >> 1;

    __shared__ float LH[TO][71];   // 18,176 B

    int tid = threadIdx.x;
    float th_h = 0.2f * (1.5f * __uint_as_float(mxh[m]));
    float th_v = 0.2f * (1.5f * __uint_as_float(mxv[m]));
    float th_d = 0.2f * (1.5f * __uint_as_float(mxd[m]));
    const float* am = a + (size_t)m * n * n;
    const float* hm = h + (size_t)m * n * n;
    const float* vm = v + (size_t)m * n * n;
    const float* dm = d + (size_t)m * n * n;

    // column idwt: 8 groups of 8 il-rows x 35 jc = 280 tasks
    auto coltask = [&](int task) {
        int g = task / 35, jc = task % 35;
        int jcg = jc0 + jc; if (jcg > n - 1) jcg = n - 1;
        // batched preload: rows jr0+4g .. jr0+4g+6, all 4 bands
        float Ar[7], Hr[7], Vr[7], Dr[7];
#pragma unroll
        for (int rr = 0; rr < 7; ++rr) {
            int jr = jr0 + 4 * g + rr; if (jr > n - 1) jr = n - 1;
            size_t o = (size_t)jr * n + jcg;
            Ar[rr] = am[o];
            Hr[rr] = hm[o];
            Vr[rr] = vm[o];
            Dr[rr] = dm[o];
        }
#pragma unroll
        for (int rr = 0; rr < 7; ++rr) {
            Hr[rr] = soft_enh(Hr[rr], th_h);
            Vr[rr] = soft_enh(Vr[rr], th_v);
            Dr[rr] = soft_enh(Dr[rr], th_d);
        }
#pragma unroll
        for (int pass = 0; pass < 2; ++pass) {
            int P = 2 * g + pass;                // 4-output group index
            float acc_lo[4], acc_hi[4];
#pragma unroll
            for (int k = 0; k < 4; ++k) { acc_lo[k] = 0.f; acc_hi[k] = 0.f; }
#pragma unroll
            for (int rl = 0; rl < 5; ++rl) {
                int rr = 2 * pass + rl;          // row index into preload
                float av = Ar[rr], hv = Hr[rr], vv = Vr[rr], dv = Dr[rr];
#pragma unroll
                for (int t = 0; t < 8; ++t) {
                    int k = 2 * rl + t - 6;      // compile-time per iteration
                    if (k >= 0 && k < 4) {
                        acc_lo[k] = fmaf(REC_LO[t], av, fmaf(REC_HI[t], hv, acc_lo[k]));
                        acc_hi[k] = fmaf(REC_LO[t], vv, fmaf(REC_HI[t], dv, acc_hi[k]));
                    }
                }
            }
#pragma unroll
            for (int k = 0; k < 4; ++k) {
                LH[4 * P + k][jc] = acc_lo[k];
                LH[4 * P + k][35 + jc] = acc_hi[k];
            }
        }
    };
    coltask(tid);                  // tid < 280 always (256 threads)
    if (tid + 256 < 8 * 35) coltask(tid + 256);
    __syncthreads();

    // row idwt -> out tile
    for (int e = tid; e < TO * TO; e += 256) {
        int il = e >> 6, ul = e & 63;
        int t0 = ul & 1;
        float acc = 0.f;
#pragma unroll
        for (int s = 0; s < 4; ++s) {
            int t = t0 + 2 * s;
            int c = (ul + 6 - t) >> 1;
            acc = fmaf(REC_LO[t], LH[il][c], acc);
            acc = fmaf(REC_HI[t], LH[il][35 + c], acc);
        }
        int gi = i0 + il, gu = u0 + ul;
        if (gi < Ho && gu < Ho)
            out[((size_t)m * Ho + gi) * Ho + gu] = acc;
    }
}

extern "C" void kernel_launch(void* const* d_in, const int* in_sizes, int n_in,
                              void* d_out, int out_size, void* d_ws, size_t ws_size,
                              hipStream_t stream) {
    const float* x = (const float*)d_in[0];
    float* out = (float*)d_out;
    float* ws = (float*)d_ws;

    const int M = 96, S1 = 510, N1 = 258, N2 = 132;
    const long S_l1 = (long)M * N1 * N1;
    const long S_l2 = (long)M * N2 * N2;

    float* aa1 = ws;
    float* h1  = aa1 + S_l1;
    float* v1  = h1 + S_l1;
    float* d1  = v1 + S_l1;
    float* a1r = d1 + S_l1;
    float* a2  = a1r + S_l1;
    float* h2  = a2 + S_l2;
    float* v2  = h2 + S_l2;
    float* d2  = v2 + S_l2;
    unsigned* th = (unsigned*)(d2 + S_l2);   // 6*96 uints

    long need = 5 * S_l1 + 4 * S_l2 + 576;
    if (ws_size < (size_t)need * sizeof(float)) return;

    unsigned *th_h1 = th, *th_v1 = th + 96, *th_d1 = th + 192;
    unsigned *th_h2 = th + 288, *th_v2 = th + 384, *th_d2 = th + 480;

    hipMemsetAsync(th, 0, 576 * sizeof(unsigned), stream);

    // Level 1 decomposition: x(510) -> bands(258). 9x9 tiles per image.
    fused_dwt2_k<<<9 * 9 * M, 256, 0, stream>>>(x, S1, N1, 9, aa1, h1, v1, d1,
                                                th_h1, th_v1, th_d1);
    // Level 2 decomposition: aa1(258) -> bands(132). 5x5 tiles.
    fused_dwt2_k<<<5 * 5 * M, 256, 0, stream>>>(aa1, N1, N2, 5, a2, h2, v2, d2,
                                                th_h2, th_v2, th_d2);
    // Level 2 reconstruction: (132) -> a1r(258). 5x5 tiles of 64.
    fused_idwt2_k<<<5 * 5 * M, 256, 0, stream>>>(a2, h2, v2, d2, th_h2, th_v2, th_d2,
                                                 N2, N1, 5, a1r);
    // Level 1 reconstruction: (258) -> out(510). 8x8 tiles of 64.
    fused_idwt2_k<<<8 * 8 * M, 256, 0, stream>>>(a1r, h1, v1, d1, th_h1, th_v1, th_d1,
                                                 N1, S1, 8, out);
}

// Round 3
// 335.662 us; speedup vs baseline: 1.0745x; 1.0044x over previous
//
#include <hip/hip_runtime.h>

// db4 filters as compile-time constants (immediates / s_mov, no K$ loads)
__device__ constexpr float DEC_LO[8] = {
    -0.010597401784997278f, 0.032883011666982945f, 0.030841381835986965f,
    -0.18703481171888114f, -0.02798376941698385f, 0.6308807679295904f,
    0.7148465705525415f, 0.23037781330885523f};
__device__ constexpr float DEC_HI[8] = {
    -0.23037781330885523f, 0.7148465705525415f, -0.6308807679295904f,
    -0.02798376941698385f, 0.18703481171888114f, 0.030841381835986965f,
    -0.032883011666982945f, -0.010597401784997278f};
__device__ constexpr float REC_LO[8] = {
    0.23037781330885523f, 0.7148465705525415f, 0.6308807679295904f,
    -0.02798376941698385f, -0.18703481171888114f, 0.030841381835986965f,
    0.032883011666982945f, -0.010597401784997278f};
__device__ constexpr float REC_HI[8] = {
    -0.010597401784997278f, -0.032883011666982945f, 0.030841381835986965f,
    0.18703481171888114f, -0.02798376941698385f, -0.6308807679295904f,
    0.7148465705525415f, -0.23037781330885523f};

__device__ __forceinline__ float soft_enh(float v, float th) {
    float e = 1.5f * v;
    float a = fabsf(e) - th;
    return a > 0.0f ? copysignf(a, e) : 0.0f;
}

#define TB 32
#define TO 64

// Raw input tile staged to LDS: 70 rows x 76-float stride (cols 0..69 used).
// Stride 76: (76r + 8q) % 4 == 0 -> every float4 row-DWT read is 16B-aligned,
// and start banks (12r+8q)%32 tile all 32 banks uniformly (canonical b128
// pattern, conflict-free). 84 chunks x 64 floats = 5376 slots.
#define RAW_STRIDE 76
#define RAW_CHUNKS 84   // ceil(70*76 / 64)

// Fused 2D DWT. Staging via async global_load_lds (fire-and-forget DMA:
// no VGPR round-trip, no per-task vmcnt drain - the only wait is the
// barrier). Symmetric reflection is folded into the per-lane GLOBAL source
// address; LDS dest stays linear (HW requirement). Edge tiles take the
// same path as interior tiles: zero divergence.
__global__ __launch_bounds__(256, 4) void fused_dwt2_k(
    const float* __restrict__ x, int S, int Nc, int tiles,
    float* __restrict__ aa, float* __restrict__ da,
    float* __restrict__ ad, float* __restrict__ dd,
    unsigned* __restrict__ mx_da, unsigned* __restrict__ mx_ad,
    unsigned* __restrict__ mx_dd)
{
    int b = blockIdx.x;
    int tx = b % tiles, ty = (b / tiles) % tiles, m = b / (tiles * tiles);
    int jh0 = ty * TB, jw0 = tx * TB;
    int r0 = 2 * jh0 - 6, c0 = 2 * jw0 - 6;
    const float* xm = x + (size_t)m * S * S;

    __shared__ float raw[RAW_CHUNKS * 64];   // 21,504 B
    __shared__ float RB[70][68];             // 19,040 B

    int tid = threadIdx.x;
    int wv = tid >> 6, ln = tid & 63;

    // --- async stage: 21 chunks per wave, all in flight before the barrier
    for (int j = 0; j < RAW_CHUNKS / 4; ++j) {
        int w = wv * (RAW_CHUNKS / 4) + j;
        unsigned idx = (unsigned)(64 * w + ln);
        if (idx > 5319u) idx = 5319u;        // tail lanes: duplicate-safe
        unsigned r = idx / RAW_STRIDE;
        unsigned c = idx - r * RAW_STRIDE;
        if (c > 69u) c = 69u;                // pad cols: value unused
        int pr = r0 + (int)r;
        pr = pr < 0 ? -1 - pr : pr;
        pr = pr >= S ? 2 * S - 1 - pr : pr;
        int pc = c0 + (int)c;
        pc = pc < 0 ? -1 - pc : pc;
        pc = pc >= S ? 2 * S - 1 - pc : pc;
        const float* g = xm + (size_t)pr * S + pc;
#if defined(__has_builtin) && __has_builtin(__builtin_amdgcn_global_load_lds)
        __builtin_amdgcn_global_load_lds(
            (const __attribute__((address_space(1))) void*)g,
            (__attribute__((address_space(3))) void*)(&raw[64 * w]),
            4, 0, 0);
#else
        raw[64 * w + ln] = *g;
#endif
    }
    __syncthreads();   // compiler drains vmcnt before s_barrier

    // --- row dwt from LDS: 560 tasks (row r, quad q), 4 outputs each
    for (int e = tid; e < 560; e += 256) {
        int r = e >> 3, q = e & 7;
        const float* base = &raw[RAW_STRIDE * r + 8 * q];
        float f[16];
        float4 A = *reinterpret_cast<const float4*>(base);
        float4 B = *reinterpret_cast<const float4*>(base + 4);
        float4 C = *reinterpret_cast<const float4*>(base + 8);
        float4 D = *reinterpret_cast<const float4*>(base + 12);
        f[0] = A.x; f[1] = A.y; f[2] = A.z; f[3] = A.w;
        f[4] = B.x; f[5] = B.y; f[6] = B.z; f[7] = B.w;
        f[8] = C.x; f[9] = C.y; f[10] = C.z; f[11] = C.w;
        f[12] = D.x; f[13] = D.y; f[14] = D.z; f[15] = D.w;
        float lo[4], hi[4];
#pragma unroll
        for (int i = 0; i < 4; ++i) {
            float alo = 0.f, ahi = 0.f;
#pragma unroll
            for (int t = 0; t < 8; ++t) {
                float v = f[2 * i + 7 - t];
                alo = fmaf(DEC_LO[t], v, alo);
                ahi = fmaf(DEC_HI[t], v, ahi);
            }
            lo[i] = alo; hi[i] = ahi;
        }
        int c4 = 4 * q;
        *reinterpret_cast<float4*>(&RB[r][c4]) = make_float4(lo[0], lo[1], lo[2], lo[3]);
        *reinterpret_cast<float4*>(&RB[r][32 + c4]) = make_float4(hi[0], hi[1], hi[2], hi[3]);
    }
    __syncthreads();

    // col dwt: thread owns (jj, 4 consecutive ii), two register-light passes
    int jj = tid & 31, g = tid >> 5;
    int jw = jw0 + jj;
    float mh = 0.f, mv = 0.f, md = 0.f;
#pragma unroll
    for (int pass = 0; pass < 2; ++pass) {
        int rbase = 8 * g + 4 * pass;
        float L[10], H[10];
#pragma unroll
        for (int rr = 0; rr < 10; ++rr) {
            L[rr] = RB[rbase + rr][jj];
            H[rr] = RB[rbase + rr][32 + jj];
        }
#pragma unroll
        for (int k = 0; k < 2; ++k) {
            float vaa = 0.f, vda = 0.f, vad = 0.f, vdd = 0.f;
#pragma unroll
            for (int t = 0; t < 8; ++t) {
                float l = L[2 * k + 7 - t];
                float h = H[2 * k + 7 - t];
                vaa = fmaf(DEC_LO[t], l, vaa);
                vda = fmaf(DEC_HI[t], l, vda);
                vad = fmaf(DEC_LO[t], h, vad);
                vdd = fmaf(DEC_HI[t], h, vdd);
            }
            int jh = jh0 + 4 * g + 2 * pass + k;
            if (jh < Nc && jw < Nc) {
                size_t o = ((size_t)m * Nc + jh) * Nc + jw;
                aa[o] = vaa; da[o] = vda; ad[o] = vad; dd[o] = vdd;
                mh = fmaxf(mh, fabsf(vda));
                mv = fmaxf(mv, fabsf(vad));
                md = fmaxf(md, fabsf(vdd));
            }
        }
    }
#pragma unroll
    for (int off = 32; off; off >>= 1) {
        mh = fmaxf(mh, __shfl_down(mh, off));
        mv = fmaxf(mv, __shfl_down(mv, off));
        md = fmaxf(md, __shfl_down(md, off));
    }
    __shared__ float sm[3][4];
    if (ln == 0) { sm[0][wv] = mh; sm[1][wv] = mv; sm[2][wv] = md; }
    __syncthreads();
    if (tid == 0) {
        float A = fmaxf(fmaxf(sm[0][0], sm[0][1]), fmaxf(sm[0][2], sm[0][3]));
        float B = fmaxf(fmaxf(sm[1][0], sm[1][1]), fmaxf(sm[1][2], sm[1][3]));
        float C = fmaxf(fmaxf(sm[2][0], sm[2][1]), fmaxf(sm[2][2], sm[2][3]));
        atomicMax(mx_da + m, __float_as_uint(A));
        atomicMax(mx_ad + m, __float_as_uint(B));
        atomicMax(mx_dd + m, __float_as_uint(C));
    }
}

// Fused 2D IDWT. Column-IDWT: per task, preload the 7 needed band rows
// (7 rows x 4 bands = 28 floats) in one batched burst, soft-threshold in
// registers, then run both 4-output passes from registers.
__global__ __launch_bounds__(256, 4) void fused_idwt2_k(
    const float* __restrict__ a, const float* __restrict__ h,
    const float* __restrict__ v, const float* __restrict__ d,
    const unsigned* __restrict__ mxh, const unsigned* __restrict__ mxv,
    const unsigned* __restrict__ mxd,
    int n, int Ho, int tiles, float* __restrict__ out)
{
    int b = blockIdx.x;
    int tx = b % tiles, ty = (b / tiles) % tiles, m = b / (tiles * tiles);
    int i0 = ty * TO, u0 = tx * TO;
    int jr0 = i0 >> 1, jc0 = u0 >> 1;

    __shared__ float LH[TO][71];   // 18,176 B

    int tid = threadIdx.x;
    float th_h = 0.2f * (1.5f * __uint_as_float(mxh[m]));
    float th_v = 0.2f * (1.5f * __uint_as_float(mxv[m]));
    float th_d = 0.2f * (1.5f * __uint_as_float(mxd[m]));
    const float* am = a + (size_t)m * n * n;
    const float* hm = h + (size_t)m * n * n;
    const float* vm = v + (size_t)m * n * n;
    const float* dm = d + (size_t)m * n * n;

    // column idwt: 8 groups of 8 il-rows x 35 jc = 280 tasks
    auto coltask = [&](int task) {
        int g = task / 35, jc = task % 35;
        int jcg = jc0 + jc; if (jcg > n - 1) jcg = n - 1;
        // batched preload: rows jr0+4g .. jr0+4g+6, all 4 bands
        float Ar[7], Hr[7], Vr[7], Dr[7];
#pragma unroll
        for (int rr = 0; rr < 7; ++rr) {
            int jr = jr0 + 4 * g + rr; if (jr > n - 1) jr = n - 1;
            size_t o = (size_t)jr * n + jcg;
            Ar[rr] = am[o];
            Hr[rr] = hm[o];
            Vr[rr] = vm[o];
            Dr[rr] = dm[o];
        }
#pragma unroll
        for (int rr = 0; rr < 7; ++rr) {
            Hr[rr] = soft_enh(Hr[rr], th_h);
            Vr[rr] = soft_enh(Vr[rr], th_v);
            Dr[rr] = soft_enh(Dr[rr], th_d);
        }
#pragma unroll
        for (int pass = 0; pass < 2; ++pass) {
            int P = 2 * g + pass;                // 4-output group index
            float acc_lo[4], acc_hi[4];
#pragma unroll
            for (int k = 0; k < 4; ++k) { acc_lo[k] = 0.f; acc_hi[k] = 0.f; }
#pragma unroll
            for (int rl = 0; rl < 5; ++rl) {
                int rr = 2 * pass + rl;          // row index into preload
                float av = Ar[rr], hv = Hr[rr], vv = Vr[rr], dv = Dr[rr];
#pragma unroll
                for (int t = 0; t < 8; ++t) {
                    int k = 2 * rl + t - 6;      // compile-time per iteration
                    if (k >= 0 && k < 4) {
                        acc_lo[k] = fmaf(REC_LO[t], av, fmaf(REC_HI[t], hv, acc_lo[k]));
                        acc_hi[k] = fmaf(REC_LO[t], vv, fmaf(REC_HI[t], dv, acc_hi[k]));
                    }
                }
            }
#pragma unroll
            for (int k = 0; k < 4; ++k) {
                LH[4 * P + k][jc] = acc_lo[k];
                LH[4 * P + k][35 + jc] = acc_hi[k];
            }
        }
    };
    coltask(tid);                  // tid < 280 always (256 threads)
    if (tid + 256 < 8 * 35) coltask(tid + 256);
    __syncthreads();

    // row idwt -> out tile
    for (int e = tid; e < TO * TO; e += 256) {
        int il = e >> 6, ul = e & 63;
        int t0 = ul & 1;
        float acc = 0.f;
#pragma unroll
        for (int s = 0; s < 4; ++s) {
            int t = t0 + 2 * s;
            int c = (ul + 6 - t) >> 1;
            acc = fmaf(REC_LO[t], LH[il][c], acc);
            acc = fmaf(REC_HI[t], LH[il][35 + c], acc);
        }
        int gi = i0 + il, gu = u0 + ul;
        if (gi < Ho && gu < Ho)
            out[((size_t)m * Ho + gi) * Ho + gu] = acc;
    }
}

extern "C" void kernel_launch(void* const* d_in, const int* in_sizes, int n_in,
                              void* d_out, int out_size, void* d_ws, size_t ws_size,
                              hipStream_t stream) {
    const float* x = (const float*)d_in[0];
    float* out = (float*)d_out;
    float* ws = (float*)d_ws;

    const int M = 96, S1 = 510, N1 = 258, N2 = 132;
    const long S_l1 = (long)M * N1 * N1;
    const long S_l2 = (long)M * N2 * N2;

    float* aa1 = ws;
    float* h1  = aa1 + S_l1;
    float* v1  = h1 + S_l1;
    float* d1  = v1 + S_l1;
    float* a1r = d1 + S_l1;
    float* a2  = a1r + S_l1;
    float* h2  = a2 + S_l2;
    float* v2  = h2 + S_l2;
    float* d2  = v2 + S_l2;
    unsigned* th = (unsigned*)(d2 + S_l2);   // 6*96 uints

    long need = 5 * S_l1 + 4 * S_l2 + 576;
    if (ws_size < (size_t)need * sizeof(float)) return;

    unsigned *th_h1 = th, *th_v1 = th + 96, *th_d1 = th + 192;
    unsigned *th_h2 = th + 288, *th_v2 = th + 384, *th_d2 = th + 480;

    hipMemsetAsync(th, 0, 576 * sizeof(unsigned), stream);

    // Level 1 decomposition: x(510) -> bands(258). 9x9 tiles per image.
    fused_dwt2_k<<<9 * 9 * M, 256, 0, stream>>>(x, S1, N1, 9, aa1, h1, v1, d1,
                                                th_h1, th_v1, th_d1);
    // Level 2 decomposition: aa1(258) -> bands(132). 5x5 tiles.
    fused_dwt2_k<<<5 * 5 * M, 256, 0, stream>>>(aa1, N1, N2, 5, a2, h2, v2, d2,
                                                th_h2, th_v2, th_d2);
    // Level 2 reconstruction: (132) -> a1r(258). 5x5 tiles of 64.
    fused_idwt2_k<<<5 * 5 * M, 256, 0, stream>>>(a2, h2, v2, d2, th_h2, th_v2, th_d2,
                                                 N2, N1, 5, a1r);
    // Level 1 reconstruction: (258) -> out(510). 8x8 tiles of 64.
    fused_idwt2_k<<<8 * 8 * M, 256, 0, stream>>>(a1r, h1, v1, d1, th_h1, th_v1, th_d1,
                                                 N1, S1, 8, out);
}